// Round 8
// baseline (43.395 us; speedup 1.0000x reference)
//
#include <hip/hip_runtime.h>
#include <hip/hip_fp16.h>
#include <math.h>

#define B_TOTAL 2048
#define I_DIM   128
#define O_DIM   128
#define GK      68                  // G + k rows in w
#define NKNOT   71                  // G + 2k - 1
#define BT      64                  // b per block
#define BTILES  (B_TOTAL / BT)      // 32
#define RI      8                   // i per block
#define NR      (I_DIM / RI)        // 16 i-ranges
#define THREADS 512                 // 8 waves
#define SLICE_ELEMS (GK * O_DIM)    // 8704 halfs = 17408 B per i-slice
#define CHUNKS  (SLICE_ELEMS * 2 / 1024)    // 17 chunks of 1KB (64 lanes x 16B)
#define W_ELEMS ((size_t)GK * I_DIM * O_DIM)         // 1114112
#define PART_FLOATS ((size_t)NR * B_TOTAL * O_DIM)   // 4M floats = 16MB
#define WS_FULL (PART_FLOATS * 4 + W_ELEMS * 2)      // ~18.4MB
#define WS_MIN  (W_ELEMS * 2)                        // 2.23MB

__device__ __forceinline__ __half2 u2h2(unsigned u) {
    return __builtin_bit_cast(__half2, u);
}

// w (f32, [GK][I][O]) -> fp16 same layout. RNE. 1088 blocks x 256 thr.
__global__ __launch_bounds__(256)
void wcvt(const float* __restrict__ w, __half* __restrict__ wh) {
    const int e4 = blockIdx.x * 256 + threadIdx.x;
    const float4 v = ((const float4*)w)[e4];
    uint2 o;
    o.x = __builtin_bit_cast(unsigned, __floats2half2_rn(v.x, v.y));
    o.y = __builtin_bit_cast(unsigned, __floats2half2_rn(v.z, v.w));
    ((uint2*)wh)[e4] = o;
}

// grid = 32 b-tiles x 16 i-ranges = 512 blocks (2/CU), 512 threads (8 waves).
// w staged as fp16: row = 256B, so 32 lanes x 8B cover it -> the two
// half-waves handle TWO DIFFERENT b's per instruction (4 groups of 2 b).
// Per group per phase: 4x ds_read_b64 (rows g0..g0+3 of that half's b) +
// 10x v_pk_fma_f16; silu row read once per phase (same addr both halves =
// broadcast). Coefs per-wave in registers as replicated half2, broadcast
// via readlane, half-selected via cndmask. fp16 accum spans one i (5 terms),
// folded to f32 every phase.
template<bool USE_WS>
__global__ __launch_bounds__(THREADS, 4)
void flashkan_main(const float* __restrict__ x,
                   const __half* __restrict__ wh,
                   const float* __restrict__ t,
                   float* __restrict__ dst) {
    __shared__ __align__(16) __half wbuf[2][SLICE_ELEMS];   // 2 x 17408 B
    __shared__ float t_sh[NKNOT];

    const int tid  = threadIdx.x;
    const int bid  = blockIdx.x;
    const int bt   = bid >> 4;      // 0..31
    const int r    = bid & 15;      // 0..15
    const int b0   = bt * BT;
    const int i0   = r * RI;
    const int wave = tid >> 6;
    const int lane = tid & 63;
    const int h    = lane >> 5;     // half-wave -> which b of the group
    const int l32  = lane & 31;     // o-quad index (4 o's per lane)

    if (tid < NKNOT) t_sh[tid] = t[tid];
    __syncthreads();

    // ---- per-wave coef phase: lane owns (bl = lane>>3, ii = lane&7) ----
    unsigned cp0, cp1, cp2, cp3, cp4;   // replicated-half2 packed coefs
    int cg;
    {
        const int bl = lane >> 3;
        const int ii = lane & 7;
        const float xv = x[(size_t)(b0 + wave * 8 + bl) * I_DIM + (i0 + ii)];

        int ik = 3 + (int)floorf((xv + 1.0f) * 32.0f);
        ik = min(max(ik, 3), 66);
        while (ik < 66 && xv >= t_sh[ik + 1]) ++ik;
        while (ik > 3 && xv < t_sh[ik]) --ik;

        float l0, l1, l2, r0, r1, r2;
        float N0 = 1.0f, N1, N2, N3;
        l0 = xv - t_sh[ik];
        r0 = t_sh[ik + 1] - xv;
        {
            float temp = N0 / (r0 + l0);
            N0 = r0 * temp;
            N1 = l0 * temp;
        }
        l1 = xv - t_sh[ik - 1];
        r1 = t_sh[ik + 2] - xv;
        {
            float saved = 0.0f, temp;
            temp = N0 / (r0 + l1);
            N0 = saved + r0 * temp;
            saved = l1 * temp;
            temp = N1 / (r1 + l0);
            N1 = saved + r1 * temp;
            N2 = l0 * temp;
        }
        l2 = xv - t_sh[ik - 2];
        r2 = t_sh[ik + 3] - xv;
        {
            float saved = 0.0f, temp;
            temp = N0 / (r0 + l2);
            N0 = saved + r0 * temp;
            saved = l2 * temp;
            temp = N1 / (r1 + l1);
            N1 = saved + r1 * temp;
            saved = l1 * temp;
            temp = N2 / (r2 + l0);
            N2 = saved + r2 * temp;
            N3 = l0 * temp;
        }
        const float silu = xv / (1.0f + expf(-xv));

        cp0 = 0x00010001u * (unsigned)__half_as_ushort(__float2half_rn(N0));
        cp1 = 0x00010001u * (unsigned)__half_as_ushort(__float2half_rn(N1));
        cp2 = 0x00010001u * (unsigned)__half_as_ushort(__float2half_rn(N2));
        cp3 = 0x00010001u * (unsigned)__half_as_ushort(__float2half_rn(N3));
        cp4 = 0x00010001u * (unsigned)__half_as_ushort(__float2half_rn(silu));
        cg  = ik - 3;
    }

    // ---- staging: fp16 slice w[:, i_abs, :] -> wbuf[sel] ----
    auto stage = [&](int sel, int i_abs) {
        for (int c = wave; c < CHUNKS; c += 8) {          // wave-uniform loop
            const int e = c * 512 + lane * 8;             // half elem idx
            const int g = e >> 7;
            const int o = e & (O_DIM - 1);
            const __half* src = wh + ((size_t)g * I_DIM + i_abs) * O_DIM + o;
            void* dstp = (void*)((char*)&wbuf[sel][0] + c * 1024);  // uniform base
            __builtin_amdgcn_global_load_lds(
                (const __attribute__((address_space(1))) void*)src,
                (__attribute__((address_space(3))) void*)dstp,
                16, 0, 0);
        }
    };

    float4  acc32[4];
    #pragma unroll
    for (int gi = 0; gi < 4; ++gi) acc32[gi] = make_float4(0.f, 0.f, 0.f, 0.f);

    auto compute = [&](int ii, const __half* buf) {
        const char* bufc = (const char*)buf;
        // silu row (g=67): both halves read same addr -> broadcast
        const uint2 su = *(const uint2*)(bufc + 67 * 256 + l32 * 8);
        const __half2 sv0 = u2h2(su.x), sv1 = u2h2(su.y);
        #pragma unroll
        for (int gi = 0; gi < 4; ++gi) {
            const int sl0 = ((gi * 2    ) << 3) | ii;     // owner lanes (uniform)
            const int sl1 = ((gi * 2 + 1) << 3) | ii;
            const unsigned c0 = h ? __builtin_amdgcn_readlane(cp0, sl1)
                                  : __builtin_amdgcn_readlane(cp0, sl0);
            const unsigned c1 = h ? __builtin_amdgcn_readlane(cp1, sl1)
                                  : __builtin_amdgcn_readlane(cp1, sl0);
            const unsigned c2 = h ? __builtin_amdgcn_readlane(cp2, sl1)
                                  : __builtin_amdgcn_readlane(cp2, sl0);
            const unsigned c3 = h ? __builtin_amdgcn_readlane(cp3, sl1)
                                  : __builtin_amdgcn_readlane(cp3, sl0);
            const unsigned c4 = h ? __builtin_amdgcn_readlane(cp4, sl1)
                                  : __builtin_amdgcn_readlane(cp4, sl0);
            const int      g0 = h ? __builtin_amdgcn_readlane(cg, sl1)
                                  : __builtin_amdgcn_readlane(cg, sl0);

            const char* rp = bufc + g0 * 256 + l32 * 8;   // row g0 of this half's b
            const uint2 r0 = *(const uint2*)(rp);
            const uint2 r1 = *(const uint2*)(rp + 256);
            const uint2 r2 = *(const uint2*)(rp + 512);
            const uint2 r3 = *(const uint2*)(rp + 768);

            __half2 a0 = __half2(__float2half_rn(0.f), __float2half_rn(0.f));
            __half2 a1 = a0;
            a0 = __hfma2(u2h2(c0), u2h2(r0.x), a0);
            a1 = __hfma2(u2h2(c0), u2h2(r0.y), a1);
            a0 = __hfma2(u2h2(c1), u2h2(r1.x), a0);
            a1 = __hfma2(u2h2(c1), u2h2(r1.y), a1);
            a0 = __hfma2(u2h2(c2), u2h2(r2.x), a0);
            a1 = __hfma2(u2h2(c2), u2h2(r2.y), a1);
            a0 = __hfma2(u2h2(c3), u2h2(r3.x), a0);
            a1 = __hfma2(u2h2(c3), u2h2(r3.y), a1);
            a0 = __hfma2(u2h2(c4), sv0, a0);
            a1 = __hfma2(u2h2(c4), sv1, a1);

            // fold this i's 5-term fp16 partial into f32 (max accuracy)
            const float2 f0 = __half22float2(a0);
            const float2 f1 = __half22float2(a1);
            acc32[gi].x += f0.x;
            acc32[gi].y += f0.y;
            acc32[gi].z += f1.x;
            acc32[gi].w += f1.y;
        }
    };

    stage(0, i0);
    __syncthreads();   // slice 0 landed (compiler drains vmcnt at barrier)

    for (int iib = 0; iib < RI; iib += 2) {
        stage(1, i0 + iib + 1);                 // prefetch into buf 1
        compute(iib, wbuf[0]);
        __syncthreads();                        // buf1 landed, buf0 reads done
        if (iib + 2 < RI) stage(0, i0 + iib + 2);
        compute(iib + 1, wbuf[1]);
        __syncthreads();
    }

    // ---- epilogue: each lane stores its half's b, float4 ----
    #pragma unroll
    for (int gi = 0; gi < 4; ++gi) {
        const int b = b0 + wave * 8 + gi * 2 + h;
        const float4 a = acc32[gi];
        if (USE_WS) {
            float4* dp = (float4*)(dst + ((size_t)r * B_TOTAL + b) * O_DIM) + l32;
            *dp = a;
        } else {
            float* dp = dst + (size_t)b * O_DIM + l32 * 4;
            atomicAdd(dp,     a.x);
            atomicAdd(dp + 1, a.y);
            atomicAdd(dp + 2, a.z);
            atomicAdd(dp + 3, a.w);
        }
    }
}

// Reduce: out[b][o] = sum_r ws[r][b][o]
__global__ __launch_bounds__(256)
void flashkan_reduce(const float* __restrict__ ws, float* __restrict__ out) {
    const int f = blockIdx.x * 256 + threadIdx.x;       // < 65536
    const float4* base = (const float4*)ws + f;
    float4 s = make_float4(0.0f, 0.0f, 0.0f, 0.0f);
    #pragma unroll
    for (int r2 = 0; r2 < NR; ++r2) {
        const float4 v = base[(size_t)r2 * (B_TOTAL * O_DIM / 4)];
        s.x += v.x; s.y += v.y; s.z += v.z; s.w += v.w;
    }
    ((float4*)out)[f] = s;
}

extern "C" void kernel_launch(void* const* d_in, const int* in_sizes, int n_in,
                              void* d_out, int out_size, void* d_ws, size_t ws_size,
                              hipStream_t stream) {
    const float* x = (const float*)d_in[0];
    const float* w = (const float*)d_in[1];
    const float* t = (const float*)d_in[2];
    float* out = (float*)d_out;

    dim3 grid(BTILES * NR);     // 512 blocks = 2/CU
    dim3 block(THREADS);
    const int cvt_blocks = (int)(W_ELEMS / 4 / 256);    // 1088

    if (ws_size >= WS_FULL) {
        float* part = (float*)d_ws;
        __half* whp = (__half*)((char*)d_ws + PART_FLOATS * 4);
        wcvt<<<cvt_blocks, 256, 0, stream>>>(w, whp);
        flashkan_main<true><<<grid, block, 0, stream>>>(x, whp, t, part);
        flashkan_reduce<<<B_TOTAL * O_DIM / 4 / 256, 256, 0, stream>>>(part, out);
    } else {
        __half* whp = (__half*)d_ws;    // needs 2.23MB
        hipMemsetAsync(out, 0, (size_t)out_size * sizeof(float), stream);
        wcvt<<<cvt_blocks, 256, 0, stream>>>(w, whp);
        flashkan_main<false><<<grid, block, 0, stream>>>(x, whp, t, out);
    }
}

// Round 9
// 30.950 us; speedup vs baseline: 1.4021x; 1.4021x over previous
//
#include <hip/hip_runtime.h>
#include <math.h>

#define B_TOTAL 2048
#define I_DIM   128
#define O_DIM   128
#define GK      68                  // G + k rows in w
#define NKNOT   71                  // G + 2k - 1
#define W_ELEMS ((size_t)GK * I_DIM * O_DIM)    // 1114112
#define WS_MIN  (W_ELEMS * 2)                   // 2.23 MB bf16 copy

__device__ __forceinline__ float rdlanef(float v, int l) {
    return __int_as_float(__builtin_amdgcn_readlane(__float_as_int(v), l));
}
__device__ __forceinline__ unsigned short f2bf(float f) {   // RNE
    unsigned u = __float_as_uint(f);
    return (unsigned short)((u + 0x7fffu + ((u >> 16) & 1u)) >> 16);
}
__device__ __forceinline__ float bflo(unsigned u) { return __uint_as_float(u << 16); }
__device__ __forceinline__ float bfhi(unsigned u) { return __uint_as_float(u & 0xffff0000u); }

// w f32 [GK][I][O] -> bf16 [I][GK][O] (transpose g<->i, o innermost).
// 1088 blocks x 256 thr; 8 (g,i) pairs/block x 32 o-quads. All coalesced.
__global__ __launch_bounds__(256)
void wcvt(const float* __restrict__ w, unsigned short* __restrict__ wbf) {
    const int tid = threadIdx.x;
    const int p   = blockIdx.x * 8 + (tid >> 5);    // (g,i) in source order
    const int oq  = (tid & 31) * 4;
    const int g   = p >> 7;
    const int i   = p & 127;
    const float4 v = *(const float4*)(w + (size_t)p * O_DIM + oq);
    ushort4 o4;
    o4.x = f2bf(v.x); o4.y = f2bf(v.y); o4.z = f2bf(v.z); o4.w = f2bf(v.w);
    *(ushort4*)(wbf + ((size_t)i * GK + g) * O_DIM + oq) = o4;
}

// One block per b: 256 thr = 4 waves, wave w handles i in [32w, 32w+32).
// No staging: direct coalesced gathers from L2-resident bf16 w (2.23MB < 4MB
// per-XCD L2). Lane covers o = {2*lane, 2*lane+1} (one dword = 2 bf16).
// Rows g0..g0+3 of (i) are contiguous in [I][GK][O] -> one base + imm offsets.
// Coefs: lane l<32 owns i = 32w+l, broadcast via readlane (SGPR operands).
// Cross-wave i-partials reduced via tiny LDS psum.
__global__ __launch_bounds__(256, 8)
void flashkan_gather(const float* __restrict__ x,
                     const unsigned short* __restrict__ wbf,
                     const float* __restrict__ t,
                     float* __restrict__ out) {
    __shared__ float t_sh[NKNOT];
    __shared__ float psum[4][O_DIM];

    const int tid  = threadIdx.x;
    const int b    = blockIdx.x;
    const int wave = tid >> 6;
    const int lane = tid & 63;
    const int l32  = lane & 31;

    if (tid < NKNOT) t_sh[tid] = t[tid];
    __syncthreads();

    // ---- coef phase: every lane computes i = wave*32 + (lane&31) ----
    float cf0, cf1, cf2, cf3, cf4;
    int   cg;
    {
        const float xv = x[(size_t)b * I_DIM + wave * 32 + l32];

        int ik = 3 + (int)floorf((xv + 1.0f) * 32.0f);
        ik = min(max(ik, 3), 66);
        while (ik < 66 && xv >= t_sh[ik + 1]) ++ik;
        while (ik > 3 && xv < t_sh[ik]) --ik;

        float l0, l1, l2, r0, r1, r2;
        float N0 = 1.0f, N1, N2, N3;
        l0 = xv - t_sh[ik];
        r0 = t_sh[ik + 1] - xv;
        {
            float temp = N0 / (r0 + l0);
            N0 = r0 * temp;
            N1 = l0 * temp;
        }
        l1 = xv - t_sh[ik - 1];
        r1 = t_sh[ik + 2] - xv;
        {
            float saved = 0.0f, temp;
            temp = N0 / (r0 + l1);
            N0 = saved + r0 * temp;
            saved = l1 * temp;
            temp = N1 / (r1 + l0);
            N1 = saved + r1 * temp;
            N2 = l0 * temp;
        }
        l2 = xv - t_sh[ik - 2];
        r2 = t_sh[ik + 3] - xv;
        {
            float saved = 0.0f, temp;
            temp = N0 / (r0 + l2);
            N0 = saved + r0 * temp;
            saved = l2 * temp;
            temp = N1 / (r1 + l1);
            N1 = saved + r1 * temp;
            saved = l1 * temp;
            temp = N2 / (r2 + l0);
            N2 = saved + r2 * temp;
            N3 = l0 * temp;
        }
        cf0 = N0; cf1 = N1; cf2 = N2; cf3 = N3;
        cf4 = xv / (1.0f + expf(-xv));
        cg  = ik - 3;
    }

    // ---- gather-accumulate over this wave's 32 i ----
    const int i_base = wave * 32;
    float ax = 0.0f, ay = 0.0f;

    #pragma unroll
    for (int k = 0; k < 32; ++k) {
        const float c0 = rdlanef(cf0, k);
        const float c1 = rdlanef(cf1, k);
        const float c2 = rdlanef(cf2, k);
        const float c3 = rdlanef(cf3, k);
        const float c4 = rdlanef(cf4, k);
        const int   g0 = __builtin_amdgcn_readlane(cg, k);

        const int i = i_base + k;
        const unsigned* rp = (const unsigned*)(wbf + (((size_t)i * GK + g0) << 7)) + lane;
        const unsigned* sp = (const unsigned*)(wbf + (((size_t)i * GK + 67) << 7)) + lane;
        const unsigned u0 = rp[0];      // row g0
        const unsigned u1 = rp[64];     // row g0+1 (+256B)
        const unsigned u2 = rp[128];    // row g0+2
        const unsigned u3 = rp[192];    // row g0+3
        const unsigned u4 = *sp;        // silu row (g=67)

        ax += c0 * bflo(u0) + c1 * bflo(u1) + c2 * bflo(u2)
            + c3 * bflo(u3) + c4 * bflo(u4);
        ay += c0 * bfhi(u0) + c1 * bfhi(u1) + c2 * bfhi(u2)
            + c3 * bfhi(u3) + c4 * bfhi(u4);
    }

    psum[wave][lane * 2]     = ax;
    psum[wave][lane * 2 + 1] = ay;
    __syncthreads();

    if (tid < O_DIM) {
        out[(size_t)b * O_DIM + tid] =
            psum[0][tid] + psum[1][tid] + psum[2][tid] + psum[3][tid];
    }
}

// Fallback (ws too small for bf16 copy): direct f32 gather, same structure.
__global__ __launch_bounds__(256)
void flashkan_gather_f32(const float* __restrict__ x,
                         const float* __restrict__ w,
                         const float* __restrict__ t,
                         float* __restrict__ out) {
    __shared__ float t_sh[NKNOT];
    __shared__ float psum[4][O_DIM];

    const int tid  = threadIdx.x;
    const int b    = blockIdx.x;
    const int wave = tid >> 6;
    const int lane = tid & 63;
    const int l32  = lane & 31;

    if (tid < NKNOT) t_sh[tid] = t[tid];
    __syncthreads();

    float cf0, cf1, cf2, cf3, cf4;
    int   cg;
    {
        const float xv = x[(size_t)b * I_DIM + wave * 32 + l32];
        int ik = 3 + (int)floorf((xv + 1.0f) * 32.0f);
        ik = min(max(ik, 3), 66);
        while (ik < 66 && xv >= t_sh[ik + 1]) ++ik;
        while (ik > 3 && xv < t_sh[ik]) --ik;
        float l0, l1, l2, r0, r1, r2;
        float N0 = 1.0f, N1, N2, N3;
        l0 = xv - t_sh[ik];  r0 = t_sh[ik + 1] - xv;
        { float temp = N0 / (r0 + l0); N0 = r0 * temp; N1 = l0 * temp; }
        l1 = xv - t_sh[ik - 1];  r1 = t_sh[ik + 2] - xv;
        { float saved = 0.0f, temp;
          temp = N0 / (r0 + l1); N0 = saved + r0 * temp; saved = l1 * temp;
          temp = N1 / (r1 + l0); N1 = saved + r1 * temp; N2 = l0 * temp; }
        l2 = xv - t_sh[ik - 2];  r2 = t_sh[ik + 3] - xv;
        { float saved = 0.0f, temp;
          temp = N0 / (r0 + l2); N0 = saved + r0 * temp; saved = l2 * temp;
          temp = N1 / (r1 + l1); N1 = saved + r1 * temp; saved = l1 * temp;
          temp = N2 / (r2 + l0); N2 = saved + r2 * temp; N3 = l0 * temp; }
        cf0 = N0; cf1 = N1; cf2 = N2; cf3 = N3;
        cf4 = xv / (1.0f + expf(-xv));
        cg  = ik - 3;
    }

    const int i_base = wave * 32;
    float ax = 0.0f, ay = 0.0f;
    #pragma unroll 8
    for (int k = 0; k < 32; ++k) {
        const float c0 = rdlanef(cf0, k);
        const float c1 = rdlanef(cf1, k);
        const float c2 = rdlanef(cf2, k);
        const float c3 = rdlanef(cf3, k);
        const float c4 = rdlanef(cf4, k);
        const int   g0 = __builtin_amdgcn_readlane(cg, k);
        const int i = i_base + k;
        const float2* base = (const float2*)(w + (size_t)i * O_DIM) + lane;
        const size_t rs = (size_t)I_DIM * O_DIM / 2;    // row stride in float2
        const float2 v0 = base[(size_t)g0 * rs];
        const float2 v1 = base[(size_t)(g0 + 1) * rs];
        const float2 v2 = base[(size_t)(g0 + 2) * rs];
        const float2 v3 = base[(size_t)(g0 + 3) * rs];
        const float2 v4 = base[(size_t)(GK - 1) * rs];
        ax += c0 * v0.x + c1 * v1.x + c2 * v2.x + c3 * v3.x + c4 * v4.x;
        ay += c0 * v0.y + c1 * v1.y + c2 * v2.y + c3 * v3.y + c4 * v4.y;
    }

    psum[wave][lane * 2]     = ax;
    psum[wave][lane * 2 + 1] = ay;
    __syncthreads();
    if (tid < O_DIM) {
        out[(size_t)b * O_DIM + tid] =
            psum[0][tid] + psum[1][tid] + psum[2][tid] + psum[3][tid];
    }
}

extern "C" void kernel_launch(void* const* d_in, const int* in_sizes, int n_in,
                              void* d_out, int out_size, void* d_ws, size_t ws_size,
                              hipStream_t stream) {
    const float* x = (const float*)d_in[0];
    const float* w = (const float*)d_in[1];
    const float* t = (const float*)d_in[2];
    float* out = (float*)d_out;

    if (ws_size >= WS_MIN) {
        unsigned short* wbf = (unsigned short*)d_ws;
        wcvt<<<(int)(W_ELEMS / (8 * 128)), 256, 0, stream>>>(w, wbf);  // 1088 blocks
        flashkan_gather<<<B_TOTAL, 256, 0, stream>>>(x, wbf, t, out);
    } else {
        flashkan_gather_f32<<<B_TOTAL, 256, 0, stream>>>(x, w, t, out);
    }
}